// Round 10
// baseline (165.491 us; speedup 1.0000x reference)
//
#include <hip/hip_runtime.h>

// MultiHeadSelfAttention: B=8 N=1024 E=768 H=12 D=64
// Pipeline: cvt(x) / transpose-cvt(Wqkv,Wfc)
//           -> GEMM1: 256^2 8-phase bf16 mfma (m201 template), epilogue ->
//              qh/kh [b,h,n,d] (Q pre-scaled) + V DIRECT to vt [b,h,d,n]
//           -> flash attention (K/V LDS dbuf + XOR swizzle, swapped QK^T)
//           -> GEMM2: proven 2-phase dbuf 128^2 (R6), f32 out + bias
//
// GEMM1 stage schedule (R9's race FIXED). Read footprint per phase:
//   A reads: P1/P5 rows wr*128+0..63, P3/P7 rows wr*128+64..127
//     -> A-lo(0..127) AND A-hi(128..255) both have last-read at P3 (grp1)/P7 (grp2)
//   B reads: P1/P5 rows wc*64+0..31, P2/P6 rows wc*64+32..63
//     -> B-lo/B-hi both last-read at P2 (grp1)/P6 (grp2)
// Stages (all after the region's last read, >=1 barrier):
//   P1: A1-hi(T1)    P3: B0-lo(T2)   P4: B0-hi(T2) | vmcnt(4) drains T1
//   P5: A0-lo(T2)    P6: A0-hi(T2)   P7: B1-lo(T3)
//   P8: B1-hi(T3)+A1-lo(T3)          | vmcnt(6) drains T2
// In-flight audited at t=0 / steady / tail (t=5: P4 vmcnt(0)).
// Loop forced rolled (#pragma unroll 1) -- I$ fits (~4KB vs R7's 38KB unroll).
// ws usage: ~80 MB.

typedef unsigned short u16;
typedef unsigned int u32;
typedef __attribute__((ext_vector_type(8))) short short8;  // 8 x bf16 (4 VGPR)
typedef __attribute__((ext_vector_type(4))) float f32x4;

#define DEV static __device__ __forceinline__

DEV u16 f2bf(float f) {  // round-to-nearest-even f32 -> bf16 bits
  union { float f; u32 u; } v; v.f = f;
  return (u16)((v.u + 0x7FFFu + ((v.u >> 16) & 1u)) >> 16);
}

DEV void gload_lds16(const void* g, void* l) {
  // LDS dest is wave-uniform base; HW writes lane i at base + i*16B.
  __builtin_amdgcn_global_load_lds(
      (const __attribute__((address_space(1))) void*)g,
      (__attribute__((address_space(3))) void*)l, 16, 0, 0);
}

// ---------------- f32 -> bf16 elementwise (8 elems/thread) ----------------
__global__ void cvt_bf16_kernel(const float* __restrict__ in, u16* __restrict__ out, int n8) {
  int idx = blockIdx.x * blockDim.x + threadIdx.x;
  int stride = gridDim.x * blockDim.x;
  for (int i = idx; i < n8; i += stride) {
    float4 a = reinterpret_cast<const float4*>(in)[2 * i];
    float4 b = reinterpret_cast<const float4*>(in)[2 * i + 1];
    uint4 o;
    o.x = f2bf(a.x) | ((u32)f2bf(a.y) << 16);
    o.y = f2bf(a.z) | ((u32)f2bf(a.w) << 16);
    o.z = f2bf(b.x) | ((u32)f2bf(b.y) << 16);
    o.w = f2bf(b.z) | ((u32)f2bf(b.w) << 16);
    reinterpret_cast<uint4*>(out)[i] = o;
  }
}

// ------------- W [K][Nn] f32 -> Wt [Nn][K] bf16, 64x64 LDS tiles -------------
__global__ void trcvt_kernel(const float* __restrict__ in, u16* __restrict__ out,
                             int K, int Nn) {
  __shared__ u16 tile[64][72];
  int ntiles = Nn >> 6;
  int tk = blockIdx.x / ntiles, tn = blockIdx.x % ntiles;
  int k0 = tk << 6, n0 = tn << 6;
  int t = threadIdx.x;
  int r = t >> 4;            // 0..15
  int c4 = (t & 15) << 2;    // 0,4,..,60
#pragma unroll
  for (int ps = 0; ps < 4; ++ps) {
    int k = r + ps * 16;
    float4 v = *reinterpret_cast<const float4*>(&in[(size_t)(k0 + k) * Nn + n0 + c4]);
    tile[c4 + 0][k] = f2bf(v.x);
    tile[c4 + 1][k] = f2bf(v.y);
    tile[c4 + 2][k] = f2bf(v.z);
    tile[c4 + 3][k] = f2bf(v.w);
  }
  __syncthreads();
  int nr = t >> 3;           // 0..31
  int c8 = (t & 7) << 3;     // 0..56
#pragma unroll
  for (int ps = 0; ps < 2; ++ps) {
    int n = nr + ps * 32;
    uint4 v = *reinterpret_cast<const uint4*>(&tile[n][c8]);
    *reinterpret_cast<uint4*>(&out[(size_t)(n0 + n) * K + k0 + c8]) = v;
  }
}

// ---------------- GEMM1: 256^2 8-phase, K=768, qkv epilogue ----------------
__global__ __launch_bounds__(512, 2) void gemm8p_qkv(
    const u16* __restrict__ A, const u16* __restrict__ Bt,
    const float* __restrict__ bias,
    u16* __restrict__ qh, u16* __restrict__ kh, u16* __restrict__ vt) {
  __shared__ u16 As[2][256 * 64];   // 64 KB
  __shared__ u16 Bs[2][256 * 64];   // 64 KB
  int wg = blockIdx.x;
  wg = (wg & 7) * 36 + (wg >> 3);   // XCD swizzle, nwg=288 (288/8=36)
  const int tm = wg / 9, tn = wg % 9;
  const int m0 = tm << 8, n0 = tn << 8;
  const int tid = threadIdx.x;
  const int w = tid >> 6, lane = tid & 63;
  const int g = lane >> 4, p = lane & 15;
  const int wr = w >> 2, wc = w & 3;        // wave -> 128x64 out

  // staging: one gload covers 64 rows (8/wave); LDS(row,c)=global chunk c^(row&7)
  const int srow8 = lane >> 3;              // 0..7
  const int sch = (lane & 7) ^ srow8;       // pre-swizzled source chunk
  const u16* Abase = A + (size_t)(m0 + w * 8 + srow8) * 768 + sch * 8;
  const u16* Bbase = Bt + (size_t)(n0 + w * 8 + srow8) * 768 + sch * 8;
  // frag read: chunk q of row r at LDS chunk q^(r&7); r&7 == p&7 here
  const int c0 = (g ^ (p & 7)) << 3;
  const int c1 = ((4 + g) ^ (p & 7)) << 3;

  u16* A0 = As[0]; u16* A1 = As[1];
  u16* B0 = Bs[0]; u16* B1 = Bs[1];

  f32x4 acc[8][4] = {};
  short8 af[4][2], bf[4][2];

#define STG(Xbase, XS, half, tile)                                             \
  do {                                                                         \
    gload_lds16(Xbase + (size_t)((half) * 128) * 768 + (size_t)(tile) * 64,    \
                &XS[((half) * 128 + w * 8) * 64]);                             \
    gload_lds16(Xbase + (size_t)((half) * 128 + 64) * 768 + (size_t)(tile) * 64, \
                &XS[((half) * 128 + 64 + w * 8) * 64]);                        \
  } while (0)

#define RDA(XS, moff)                                                          \
  do {                                                                         \
    _Pragma("unroll") for (int mb = 0; mb < 4; ++mb) {                         \
      const u16* ra = &XS[(wr * 128 + (moff) + mb * 16 + p) * 64];             \
      af[mb][0] = *reinterpret_cast<const short8*>(ra + c0);                   \
      af[mb][1] = *reinterpret_cast<const short8*>(ra + c1);                   \
    }                                                                          \
  } while (0)

#define RDB(XS, nb0)                                                           \
  do {                                                                         \
    _Pragma("unroll") for (int nn = 0; nn < 2; ++nn) {                         \
      const u16* rb = &XS[(wc * 64 + ((nb0) + nn) * 16 + p) * 64];             \
      bf[(nb0) + nn][0] = *reinterpret_cast<const short8*>(rb + c0);           \
      bf[(nb0) + nn][1] = *reinterpret_cast<const short8*>(rb + c1);           \
    }                                                                          \
  } while (0)

#define MM(mo, no)                                                             \
  do {                                                                         \
    _Pragma("unroll") for (int mb = 0; mb < 4; ++mb)                           \
    _Pragma("unroll") for (int nn = 0; nn < 2; ++nn) {                         \
      acc[(mo) + mb][(no) + nn] = __builtin_amdgcn_mfma_f32_16x16x32_bf16(     \
          af[mb][0], bf[(no) + nn][0], acc[(mo) + mb][(no) + nn], 0, 0, 0);    \
      acc[(mo) + mb][(no) + nn] = __builtin_amdgcn_mfma_f32_16x16x32_bf16(     \
          af[mb][1], bf[(no) + nn][1], acc[(mo) + mb][(no) + nn], 0, 0, 0);    \
    }                                                                          \
  } while (0)

#define PH_SYNC                                                                \
  __builtin_amdgcn_s_barrier();                                                \
  asm volatile("s_waitcnt lgkmcnt(0)" ::: "memory");                           \
  __builtin_amdgcn_s_setprio(1);

#define PH_END                                                                 \
  __builtin_amdgcn_s_setprio(0);                                               \
  __builtin_amdgcn_s_barrier();

  // prologue: tile0 full -> buf0 (8 loads); tile1 B-lo,B-hi,A-lo -> buf1 (6)
  STG(Abase, A0, 0, 0); STG(Abase, A0, 1, 0);
  STG(Bbase, B0, 0, 0); STG(Bbase, B0, 1, 0);
  STG(Bbase, B1, 0, 1); STG(Bbase, B1, 1, 1);
  STG(Abase, A1, 0, 1);
  asm volatile("s_waitcnt vmcnt(6)" ::: "memory");  // tile 0 landed
  __builtin_amdgcn_s_barrier();

#pragma unroll 1
  for (int t = 0; t < 6; ++t) {             // forced rolled (I$)
    const int T1 = 2 * t + 1, T2 = 2 * t + 2, T3 = 2 * t + 3;
    const bool more = (t < 5);
    // ---- P1: rd A0[wr*128+0..63], B0[wc*64+0..31]; stg A1-hi(T1) ----
    RDA(A0, 0); RDB(B0, 0);
    STG(Abase, A1, 1, T1);                  // buf1 A-hi last read at prev P7
    PH_SYNC; MM(0, 0); PH_END;
    // ---- P2: rd B0[wc*64+32..63] ----
    RDB(B0, 2);
    PH_SYNC; MM(0, 2); PH_END;
    // ---- P3: rd A0[wr*128+64..127]; stg B0-lo(T2) (B0 last read P2) ----
    RDA(A0, 64);
    if (more) STG(Bbase, B0, 0, T2);
    PH_SYNC; MM(4, 0); PH_END;
    // ---- P4: stg B0-hi(T2); gate tile T1 (counted) ----
    if (more) STG(Bbase, B0, 1, T2);
    PH_SYNC; MM(4, 2);
    __builtin_amdgcn_s_setprio(0);
    if (more) asm volatile("s_waitcnt vmcnt(4)" ::: "memory");  // T1's 4 halves in
    else      asm volatile("s_waitcnt vmcnt(0)" ::: "memory");
    __builtin_amdgcn_s_barrier();
    // ---- P5: rd A1[+0..63], B1[+0..31] (tile T1); stg A0-lo(T2) (A0 done P3) ----
    RDA(A1, 0); RDB(B1, 0);
    if (more) STG(Abase, A0, 0, T2);
    PH_SYNC; MM(0, 0); PH_END;
    // ---- P6: rd B1[+32..63]; stg A0-hi(T2) ----
    RDB(B1, 2);
    if (more) STG(Abase, A0, 1, T2);
    PH_SYNC; MM(0, 2); PH_END;
    // ---- P7: rd A1[+64..127]; stg B1-lo(T3) (B1 last read P6) ----
    RDA(A1, 64);
    if (more) STG(Bbase, B1, 0, T3);
    PH_SYNC; MM(4, 0); PH_END;
    // ---- P8: stg B1-hi(T3) + A1-lo(T3) (A1 last read P7); gate tile T2 ----
    if (more) { STG(Bbase, B1, 1, T3); STG(Abase, A1, 0, T3); }
    PH_SYNC; MM(4, 2);
    __builtin_amdgcn_s_setprio(0);
    if (more) asm volatile("s_waitcnt vmcnt(6)" ::: "memory");  // T2's 4 halves in
    __builtin_amdgcn_s_barrier();
  }
#undef STG
#undef RDA
#undef RDB
#undef MM
#undef PH_SYNC
#undef PH_END

  // ---- epilogue: split to qh/kh (Q scaled) + V direct to vt[bh][d][n] ----
  const float qscale = 0.036084391824351615f;  // 1/sqrt(768)
#pragma unroll
  for (int nb = 0; nb < 4; ++nb) {
    int ncol = n0 + wc * 64 + nb * 16 + p;
    float bv = bias[ncol];
    int h64 = ncol >> 6;                 // 0..35
    int which = h64 / 12;                // 0=q 1=k 2=v
    int hh = h64 - which * 12;
    int d = ncol & 63;
#pragma unroll
    for (int mb = 0; mb < 8; ++mb)
#pragma unroll
      for (int r = 0; r < 4; ++r) {
        int m = m0 + wr * 128 + mb * 16 + g * 4 + r;  // C/D: row=(lane>>4)*4+reg
        int bb = m >> 10, nr = m & 1023;
        float vv = acc[mb][nb][r] + bv;
        if (which == 2) {
          vt[((size_t)(bb * 12 + hh) * 64 + d) * 1024 + nr] = f2bf(vv);
        } else {
          u16* dst = which == 0 ? qh : kh;
          float sc = which == 0 ? qscale : 1.f;
          dst[(((size_t)bb * 12 + hh) * 1024 + nr) * 64 + d] = f2bf(vv * sc);
        }
      }
  }
}

// ---------------- GEMM2: proven 2-phase dbuf 128^2 (R6), f32 out ----------------
__global__ __launch_bounds__(256, 4) void gemm_bt_f32(
    const u16* __restrict__ A, const u16* __restrict__ Bt,
    const float* __restrict__ bias, float* __restrict__ Cout, int Nn) {
  __shared__ u16 As[2][128 * 32];
  __shared__ u16 Bs[2][128 * 32];
  const int nTn = Nn >> 7;
  const int nwg = gridDim.x;
  int wg = blockIdx.x;
  wg = (wg & 7) * (nwg >> 3) + (wg >> 3);   // XCD swizzle (nwg % 8 == 0)
  const int tm = wg / nTn, tn = wg % nTn;
  const int m0 = tm << 7, n0 = tn << 7;
  const int tid = threadIdx.x;
  const int w = tid >> 6, lane = tid & 63;
  const int g = lane >> 4, p = lane & 15;
  const int wr = w >> 1, wc = w & 1;

  const int srow = lane >> 2;               // 0..15
  const int schunk = (lane & 3) ^ ((srow >> 1) & 3);
  const u16* Asrc = A + (size_t)(m0 + srow) * 768 + schunk * 8;
  const u16* Bsrc = Bt + (size_t)(n0 + srow) * 768 + schunk * 8;
  const int csw = (g ^ ((p >> 1) & 3)) << 3;

  f32x4 acc[4][4] = {};

#define STAGE(kt, sbuf)                                                         \
  do {                                                                          \
    _Pragma("unroll")                                                           \
    for (int i = 0; i < 2; ++i) {                                               \
      int trow = w * 32 + i * 16;                                               \
      gload_lds16(Asrc + (size_t)trow * 768 + (kt) * 32, &As[sbuf][trow * 32]); \
      gload_lds16(Bsrc + (size_t)trow * 768 + (kt) * 32, &Bs[sbuf][trow * 32]); \
    }                                                                           \
  } while (0)

  STAGE(0, 0);
  __syncthreads();

  int buf = 0;
  for (int k = 0; k < 24; ++k) {
    const u16* as = As[buf];
    const u16* bs = Bs[buf];
    short8 af[4], bf[4];
#pragma unroll
    for (int mb = 0; mb < 4; ++mb)
      af[mb] = *reinterpret_cast<const short8*>(&as[(wr * 64 + mb * 16 + p) * 32 + csw]);
#pragma unroll
    for (int nb = 0; nb < 4; ++nb)
      bf[nb] = *reinterpret_cast<const short8*>(&bs[(wc * 64 + nb * 16 + p) * 32 + csw]);
    if (k < 23) STAGE(k + 1, buf ^ 1);
#pragma unroll
    for (int mb = 0; mb < 4; ++mb)
#pragma unroll
      for (int nb = 0; nb < 4; ++nb)
        acc[mb][nb] = __builtin_amdgcn_mfma_f32_16x16x32_bf16(af[mb], bf[nb], acc[mb][nb], 0, 0, 0);
    __syncthreads();
    buf ^= 1;
  }
#undef STAGE

#pragma unroll
  for (int nb = 0; nb < 4; ++nb) {
    int ncol = n0 + wc * 64 + nb * 16 + p;
    float bv = bias[ncol];
#pragma unroll
    for (int mb = 0; mb < 4; ++mb)
#pragma unroll
      for (int r = 0; r < 4; ++r) {
        int m = m0 + wr * 64 + mb * 16 + g * 4 + r;
        Cout[(size_t)m * Nn + ncol] = acc[mb][nb][r] + bv;
      }
  }
}

// ---------------- flash attention (R2/R6 version, unchanged) ----------------
__global__ __launch_bounds__(512, 6) void attn_kernel(
    const u16* __restrict__ qh, const u16* __restrict__ kh,
    const u16* __restrict__ vt, u16* __restrict__ ao) {
  __shared__ u16 Ks[2][64 * 64];
  __shared__ u16 Vs[2][64 * 64];
  __shared__ u16 Ps[8][16 * 64];
  const int bid = blockIdx.x;
  const int qt = bid & 7;
  const int bh = bid >> 3;
  const int b = bh / 12, h = bh % 12;
  const int tid = threadIdx.x;
  const int w = tid >> 6, lane = tid & 63;
  const int g = lane >> 4, p = lane & 15;
  const int qrow = qt * 128 + w * 16;

  const u16* qbase = qh + ((size_t)bh * 1024 + qrow + p) * 64;
  short8 qf0 = *reinterpret_cast<const short8*>(qbase + g * 8);
  short8 qf1 = *reinterpret_cast<const short8*>(qbase + 32 + g * 8);

  const int ci = w * 64 + lane;              // 0..511
  const int crow = ci >> 3;                  // 0..63
  const int csw = (ci & 7) ^ (crow & 7);     // swizzled source chunk
  const u16* ksrc = kh + (((size_t)bh * 1024 + crow) << 6) + csw * 8;
  const u16* vsrc = vt + ((size_t)bh * 64 + crow) * 1024 + csw * 8;
  u16* myp = Ps[w];

  const int sw = p & 7;
  const int c0 = (g ^ sw) << 3;
  const int c1 = ((4 + g) ^ sw) << 3;

  float m_run = -1e30f, l_run = 0.f;
  f32x4 oacc[4] = {};

  gload_lds16(ksrc, &Ks[0][w * 512]);
  gload_lds16(vsrc, &Vs[0][w * 512]);
  __syncthreads();

  int buf = 0;
  for (int kt = 0; kt < 1024; kt += 64) {
    if (kt < 960) {
      gload_lds16(ksrc + ((kt + 64) << 6), &Ks[buf ^ 1][w * 512]);
      gload_lds16(vsrc + (kt + 64), &Vs[buf ^ 1][w * 512]);
    }

    f32x4 s[4];
    __builtin_amdgcn_s_setprio(1);
#pragma unroll
    for (int jb = 0; jb < 4; ++jb) {
      const u16* kb = &Ks[buf][(jb * 16 + p) * 64];
      short8 k0 = *reinterpret_cast<const short8*>(kb + c0);
      short8 k1 = *reinterpret_cast<const short8*>(kb + c1);
      f32x4 z = {};
      z = __builtin_amdgcn_mfma_f32_16x16x32_bf16(k0, qf0, z, 0, 0, 0);
      z = __builtin_amdgcn_mfma_f32_16x16x32_bf16(k1, qf1, z, 0, 0, 0);
      s[jb] = z;
    }
    __builtin_amdgcn_s_setprio(0);

    float tmax = -1e30f;
#pragma unroll
    for (int jb = 0; jb < 4; ++jb)
#pragma unroll
      for (int r = 0; r < 4; ++r) tmax = fmaxf(tmax, s[jb][r]);
    tmax = fmaxf(tmax, __shfl_xor(tmax, 16));
    tmax = fmaxf(tmax, __shfl_xor(tmax, 32));
    float m_new = fmaxf(m_run, tmax);
    float alpha = __expf(m_run - m_new);
    float lsum = 0.f;
#pragma unroll
    for (int jb = 0; jb < 4; ++jb)
#pragma unroll
      for (int r = 0; r < 4; ++r) {
        float e = __expf(s[jb][r] - m_new);
        s[jb][r] = e;
        lsum += e;
      }
    lsum += __shfl_xor(lsum, 16);
    lsum += __shfl_xor(lsum, 32);
    l_run = l_run * alpha + lsum;
    m_run = m_new;

#pragma unroll
    for (int jb = 0; jb < 4; ++jb) {
      uint2 pk;
      pk.x = f2bf(s[jb][0]) | ((u32)f2bf(s[jb][1]) << 16);
      pk.y = f2bf(s[jb][2]) | ((u32)f2bf(s[jb][3]) << 16);
      int c = 2 * jb + (g >> 1);
      *reinterpret_cast<uint2*>(&myp[p * 64 + ((c ^ sw) << 3) + ((g & 1) << 2)]) = pk;
    }

    float al[4];
#pragma unroll
    for (int r = 0; r < 4; ++r) al[r] = __shfl(alpha, g * 4 + r);
#pragma unroll
    for (int nb = 0; nb < 4; ++nb)
#pragma unroll
      for (int r = 0; r < 4; ++r) oacc[nb][r] *= al[r];

    short8 pa0 = *reinterpret_cast<const short8*>(&myp[p * 64 + c0]);
    short8 pa1 = *reinterpret_cast<const short8*>(&myp[p * 64 + c1]);
    __builtin_amdgcn_s_setprio(1);
#pragma unroll
    for (int nb = 0; nb < 4; ++nb) {
      const u16* vb = &Vs[buf][(nb * 16 + p) * 64];
      short8 v0 = *reinterpret_cast<const short8*>(vb + c0);
      short8 v1 = *reinterpret_cast<const short8*>(vb + c1);
      oacc[nb] = __builtin_amdgcn_mfma_f32_16x16x32_bf16(pa0, v0, oacc[nb], 0, 0, 0);
      oacc[nb] = __builtin_amdgcn_mfma_f32_16x16x32_bf16(pa1, v1, oacc[nb], 0, 0, 0);
    }
    __builtin_amdgcn_s_setprio(0);

    __syncthreads();
    buf ^= 1;
  }

  float li[4];
#pragma unroll
  for (int r = 0; r < 4; ++r) li[r] = 1.f / __shfl(l_run, g * 4 + r);
  u16* obase = ao + ((size_t)(b * 1024 + qrow)) * 768 + h * 64;
#pragma unroll
  for (int nb = 0; nb < 4; ++nb)
#pragma unroll
    for (int r = 0; r < 4; ++r)
      obase[(size_t)(g * 4 + r) * 768 + nb * 16 + p] = f2bf(oacc[nb][r] * li[r]);
}

// ---------------- launch ----------------
extern "C" void kernel_launch(void* const* d_in, const int* in_sizes, int n_in,
                              void* d_out, int out_size, void* d_ws, size_t ws_size,
                              hipStream_t stream) {
  const float* x = (const float*)d_in[0];      // [8,1024,768]
  const float* Wqkv = (const float*)d_in[1];   // [768,2304]
  const float* bqkv = (const float*)d_in[2];   // [2304]
  const float* Wfc = (const float*)d_in[3];    // [768,768]
  const float* bfc = (const float*)d_in[4];    // [768]
  float* out = (float*)d_out;                  // [8,1024,768] f32

  char* ws = (char*)d_ws;
  u16* xb    = (u16*)(ws);                 // 12,582,912 B : x bf16 [8192][768]
  u16* wqkvT = (u16*)(ws + 12582912);      //  3,538,944 B : [2304][768]
  u16* wfcT  = (u16*)(ws + 16121856);      //  1,179,648 B : [768][768]
  u16* qh    = (u16*)(ws + 17301504);      // 12,582,912 B : [96][1024][64] (scaled)
  u16* kh    = (u16*)(ws + 29884416);      // 12,582,912 B : [96][1024][64]
  u16* vt    = (u16*)(ws + 55050240);      // 12,582,912 B : [96][64][1024]
  u16* ao    = (u16*)(ws + 67633152);      // 12,582,912 B : [8192][768]

  cvt_bf16_kernel<<<2048, 256, 0, stream>>>(x, xb, (8192 * 768) / 8);
  trcvt_kernel<<<12 * 36, 256, 0, stream>>>(Wqkv, wqkvT, 768, 2304);
  trcvt_kernel<<<12 * 12, 256, 0, stream>>>(Wfc, wfcT, 768, 768);
  gemm8p_qkv<<<288, 512, 0, stream>>>(xb, wqkvT, bqkv, qh, kh, vt);
  attn_kernel<<<96 * 8, 512, 0, stream>>>(qh, kh, vt, ao);
  gemm_bt_f32<<<64 * 6, 256, 0, stream>>>(ao, wfcT, bfc, out, 768);
}

// Round 11
// 142.696 us; speedup vs baseline: 1.1597x; 1.1597x over previous
//
#include <hip/hip_runtime.h>
#include <hip/hip_bf16.h>

// MultiHeadSelfAttention: B=8 N=1024 E=768 H=12 D=64
// Pipeline: cvt(x) / transpose-cvt(Wqkv,Wfc)
//           -> GEMM1 (R6 proven 2-phase dbuf 128^2; epilogue -> qh/kh + V
//              DIRECT to vt [b,h,d,n], Q pre-scaled by 1/sqrt(768)*log2e)
//           -> flash attention (R2/R6 structure + exp2-domain softmax,
//              defer-max THR=8, cvt_pk P-pack)
//           -> GEMM2 (same GEMM template, f32 out + bias)
// GEMM: 128x128 tile, BK=32, 256 thr / 4 waves, dbuf 32KB LDS, one
// __syncthreads per K-iter; LDS swizzle chunk^((row>>1)&3) (0 conflicts, R5).
// 8-phase template abandoned after 3 falsifying attempts (R3/R7/R10).
// ws usage: ~80 MB.

typedef unsigned short u16;
typedef unsigned int u32;
typedef __attribute__((ext_vector_type(8))) short short8;  // 8 x bf16 (4 VGPR)
typedef __attribute__((ext_vector_type(4))) float f32x4;

#define DEV static __device__ __forceinline__

DEV u16 f2bf(float f) {  // round-to-nearest-even f32 -> bf16 bits
  union { float f; u32 u; } v; v.f = f;
  return (u16)((v.u + 0x7FFFu + ((v.u >> 16) & 1u)) >> 16);
}

DEV u32 pk2(float lo, float hi) {  // pack 2 f32 -> 2 bf16 (RNE); compiler may fuse to v_cvt_pk_bf16_f32
  union { __hip_bfloat162 h2; u32 u; } v;
  v.h2.x = __float2bfloat16(lo);
  v.h2.y = __float2bfloat16(hi);
  return v.u;
}

DEV void gload_lds16(const void* g, void* l) {
  // LDS dest is wave-uniform base; HW writes lane i at base + i*16B.
  __builtin_amdgcn_global_load_lds(
      (const __attribute__((address_space(1))) void*)g,
      (__attribute__((address_space(3))) void*)l, 16, 0, 0);
}

// ---------------- f32 -> bf16 elementwise (8 elems/thread) ----------------
__global__ void cvt_bf16_kernel(const float* __restrict__ in, u16* __restrict__ out, int n8) {
  int idx = blockIdx.x * blockDim.x + threadIdx.x;
  int stride = gridDim.x * blockDim.x;
  for (int i = idx; i < n8; i += stride) {
    float4 a = reinterpret_cast<const float4*>(in)[2 * i];
    float4 b = reinterpret_cast<const float4*>(in)[2 * i + 1];
    uint4 o;
    o.x = f2bf(a.x) | ((u32)f2bf(a.y) << 16);
    o.y = f2bf(a.z) | ((u32)f2bf(a.w) << 16);
    o.z = f2bf(b.x) | ((u32)f2bf(b.y) << 16);
    o.w = f2bf(b.z) | ((u32)f2bf(b.w) << 16);
    reinterpret_cast<uint4*>(out)[i] = o;
  }
}

// ------------- W [K][Nn] f32 -> Wt [Nn][K] bf16, 64x64 LDS tiles -------------
__global__ void trcvt_kernel(const float* __restrict__ in, u16* __restrict__ out,
                             int K, int Nn) {
  __shared__ u16 tile[64][72];
  int ntiles = Nn >> 6;
  int tk = blockIdx.x / ntiles, tn = blockIdx.x % ntiles;
  int k0 = tk << 6, n0 = tn << 6;
  int t = threadIdx.x;
  int r = t >> 4;            // 0..15
  int c4 = (t & 15) << 2;    // 0,4,..,60
#pragma unroll
  for (int ps = 0; ps < 4; ++ps) {
    int k = r + ps * 16;
    float4 v = *reinterpret_cast<const float4*>(&in[(size_t)(k0 + k) * Nn + n0 + c4]);
    tile[c4 + 0][k] = f2bf(v.x);
    tile[c4 + 1][k] = f2bf(v.y);
    tile[c4 + 2][k] = f2bf(v.z);
    tile[c4 + 3][k] = f2bf(v.w);
  }
  __syncthreads();
  int nr = t >> 3;           // 0..31
  int c8 = (t & 7) << 3;     // 0..56
#pragma unroll
  for (int ps = 0; ps < 2; ++ps) {
    int n = nr + ps * 32;
    uint4 v = *reinterpret_cast<const uint4*>(&tile[n][c8]);
    *reinterpret_cast<uint4*>(&out[(size_t)(n0 + n) * K + k0 + c8]) = v;
  }
}

// ---------------- dbuf bf16 GEMM (R6 proven), K fixed = 768 ----------------
// MODE 0: f32 flat out.  MODE 2: epilogue -> qh/kh [b,h,n,d] (Q scaled by
// 1/sqrt(768)*log2e for exp2-domain softmax) + V DIRECT to vt [b,h,d,n].
template <int MODE>
__global__ __launch_bounds__(256, 4) void gemm_bt(
    const u16* __restrict__ A, const u16* __restrict__ Bt,
    const float* __restrict__ bias, void* __restrict__ Cout,
    u16* __restrict__ qh, u16* __restrict__ kh, u16* __restrict__ vt,
    int Nn) {
  __shared__ u16 As[2][128 * 32];   // 16 KB
  __shared__ u16 Bs[2][128 * 32];   // 16 KB
  const int nTn = Nn >> 7;
  const int nwg = gridDim.x;
  int wg = blockIdx.x;
  wg = (wg & 7) * (nwg >> 3) + (wg >> 3);   // XCD swizzle (nwg % 8 == 0)
  const int tm = wg / nTn, tn = wg % nTn;
  const int m0 = tm << 7, n0 = tn << 7;
  const int tid = threadIdx.x;
  const int w = tid >> 6, lane = tid & 63;
  const int g = lane >> 4, p = lane & 15;
  const int wr = w >> 1, wc = w & 1;        // wave -> 64x64 out at (wr*64, wc*64)

  // staging: one gload = 16 rows x 32 elems; lane = srow*4 + sc.
  // LDS(row, c) holds global chunk c ^ ((row>>1)&3) -> pre-swizzled source.
  const int srow = lane >> 2;               // 0..15
  const int schunk = (lane & 3) ^ ((srow >> 1) & 3);
  const u16* Asrc = A + (size_t)(m0 + srow) * 768 + schunk * 8;
  const u16* Bsrc = Bt + (size_t)(n0 + srow) * 768 + schunk * 8;
  // frag read: global chunk g of row (16-aligned)+p is at LDS chunk g^((p>>1)&3)
  const int csw = (g ^ ((p >> 1) & 3)) << 3;  // u16 offset within row

  f32x4 acc[4][4] = {};

#define STAGE(kt, sbuf)                                                         \
  do {                                                                          \
    _Pragma("unroll")                                                           \
    for (int i = 0; i < 2; ++i) {                                               \
      int trow = w * 32 + i * 16;                                               \
      gload_lds16(Asrc + (size_t)trow * 768 + (kt) * 32, &As[sbuf][trow * 32]); \
      gload_lds16(Bsrc + (size_t)trow * 768 + (kt) * 32, &Bs[sbuf][trow * 32]); \
    }                                                                           \
  } while (0)

  // prologue: stage tile 0 (syncthreads drains vmcnt -> tile 0 ready)
  STAGE(0, 0);
  __syncthreads();

  int buf = 0;
  for (int k = 0; k < 24; ++k) {
    const u16* as = As[buf];
    const u16* bs = Bs[buf];
    short8 af[4], bf[4];
#pragma unroll
    for (int mb = 0; mb < 4; ++mb)
      af[mb] = *reinterpret_cast<const short8*>(&as[(wr * 64 + mb * 16 + p) * 32 + csw]);
#pragma unroll
    for (int nb = 0; nb < 4; ++nb)
      bf[nb] = *reinterpret_cast<const short8*>(&bs[(wc * 64 + nb * 16 + p) * 32 + csw]);
    if (k < 23) STAGE(k + 1, buf ^ 1);
#pragma unroll
    for (int mb = 0; mb < 4; ++mb)
#pragma unroll
      for (int nb = 0; nb < 4; ++nb)
        acc[mb][nb] = __builtin_amdgcn_mfma_f32_16x16x32_bf16(af[mb], bf[nb], acc[mb][nb], 0, 0, 0);
    __syncthreads();
    buf ^= 1;
  }
#undef STAGE

  // Q scale includes log2(e): softmax runs in exp2 domain downstream.
  const float qscale = 0.05205878290161879f;  // 1/sqrt(768) * log2(e)
#pragma unroll
  for (int nb = 0; nb < 4; ++nb) {
    int ncol = n0 + wc * 64 + nb * 16 + p;
    float bv = bias[ncol];
    if (MODE == 0) {
#pragma unroll
      for (int mb = 0; mb < 4; ++mb)
#pragma unroll
        for (int r = 0; r < 4; ++r) {
          int m = m0 + wr * 64 + mb * 16 + g * 4 + r;  // C/D: row=(lane>>4)*4+reg
          ((float*)Cout)[(size_t)m * Nn + ncol] = acc[mb][nb][r] + bv;
        }
    } else {
      int h64 = ncol >> 6;                 // 0..35
      int which = h64 / 12;                // 0=q 1=k 2=v
      int hh = h64 - which * 12;
      int d = ncol & 63;
#pragma unroll
      for (int mb = 0; mb < 4; ++mb)
#pragma unroll
        for (int r = 0; r < 4; ++r) {
          int m = m0 + wr * 64 + mb * 16 + g * 4 + r;
          int bb = m >> 10, nr = m & 1023;
          float vv = acc[mb][nb][r] + bv;
          if (which == 2) {
            vt[((size_t)(bb * 12 + hh) * 64 + d) * 1024 + nr] = f2bf(vv);  // V -> [bh][d][n]
          } else {
            u16* dst = which == 0 ? qh : kh;
            float sc = which == 0 ? qscale : 1.f;
            dst[(((size_t)bb * 12 + hh) * 1024 + nr) * 64 + d] = f2bf(vv * sc);
          }
        }
    }
  }
}

// ---------------- flash attention (R2/R6 structure; exp2 softmax) ----------------
// grid: bh(96) * 8 q-tiles of 128 rows; 512 thr / 8 waves, wave owns 16 q-rows.
// S is in log2 domain (Q pre-scaled by 1/sqrt(768)*log2e): P = exp2(S - m).
// Defer-max (T13): skip O-rescale while per-tile max growth <= 8 (ratio 2^8;
// P <= 256, f32 accumulators -> safe). P-pack via cvt_pk-friendly casts.
__global__ __launch_bounds__(512, 6) void attn_kernel(
    const u16* __restrict__ qh, const u16* __restrict__ kh,
    const u16* __restrict__ vt, u16* __restrict__ ao) {
  __shared__ u16 Ks[2][64 * 64];
  __shared__ u16 Vs[2][64 * 64];
  __shared__ u16 Ps[8][16 * 64];
  const int bid = blockIdx.x;
  const int qt = bid & 7;
  const int bh = bid >> 3;
  const int b = bh / 12, h = bh % 12;
  const int tid = threadIdx.x;
  const int w = tid >> 6, lane = tid & 63;
  const int g = lane >> 4, p = lane & 15;
  const int qrow = qt * 128 + w * 16;

  const u16* qbase = qh + ((size_t)bh * 1024 + qrow + p) * 64;
  short8 qf0 = *reinterpret_cast<const short8*>(qbase + g * 8);
  short8 qf1 = *reinterpret_cast<const short8*>(qbase + 32 + g * 8);

  const int ci = w * 64 + lane;              // 0..511
  const int crow = ci >> 3;                  // 0..63
  const int csw = (ci & 7) ^ (crow & 7);     // swizzled source chunk
  const u16* ksrc = kh + (((size_t)bh * 1024 + crow) << 6) + csw * 8;
  const u16* vsrc = vt + ((size_t)bh * 64 + crow) * 1024 + csw * 8;
  u16* myp = Ps[w];

  const int sw = p & 7;
  const int c0 = (g ^ sw) << 3;
  const int c1 = ((4 + g) ^ sw) << 3;

  float m_run = -1e30f, l_run = 0.f;
  f32x4 oacc[4] = {};

  gload_lds16(ksrc, &Ks[0][w * 512]);
  gload_lds16(vsrc, &Vs[0][w * 512]);
  __syncthreads();

  int buf = 0;
  for (int kt = 0; kt < 1024; kt += 64) {
    if (kt < 960) {
      gload_lds16(ksrc + ((kt + 64) << 6), &Ks[buf ^ 1][w * 512]);
      gload_lds16(vsrc + (kt + 64), &Vs[buf ^ 1][w * 512]);
    }

    // ---- St = K Q^T (log2 domain) ----
    f32x4 s[4];
    __builtin_amdgcn_s_setprio(1);
#pragma unroll
    for (int jb = 0; jb < 4; ++jb) {
      const u16* kb = &Ks[buf][(jb * 16 + p) * 64];
      short8 k0 = *reinterpret_cast<const short8*>(kb + c0);
      short8 k1 = *reinterpret_cast<const short8*>(kb + c1);
      f32x4 z = {};
      z = __builtin_amdgcn_mfma_f32_16x16x32_bf16(k0, qf0, z, 0, 0, 0);
      z = __builtin_amdgcn_mfma_f32_16x16x32_bf16(k1, qf1, z, 0, 0, 0);
      s[jb] = z;
    }
    __builtin_amdgcn_s_setprio(0);

    // ---- tile max (row q = p; replicated over g after shfl) ----
    float tmax = -1e30f;
#pragma unroll
    for (int jb = 0; jb < 4; ++jb)
#pragma unroll
      for (int r = 0; r < 4; ++r) tmax = fmaxf(tmax, s[jb][r]);
    tmax = fmaxf(tmax, __shfl_xor(tmax, 16));
    tmax = fmaxf(tmax, __shfl_xor(tmax, 32));

    // ---- defer-max: rescale only when growth > 8 (log2 units) ----
    if (!__all(tmax - m_run <= 8.f)) {
      float m_new = fmaxf(m_run, tmax);
      float alpha = __builtin_amdgcn_exp2f(m_run - m_new);
      float al[4];
#pragma unroll
      for (int r = 0; r < 4; ++r) al[r] = __shfl(alpha, g * 4 + r);
#pragma unroll
      for (int nb = 0; nb < 4; ++nb)
#pragma unroll
        for (int r = 0; r < 4; ++r) oacc[nb][r] *= al[r];
      l_run *= alpha;
      m_run = m_new;
    }

    // ---- P = exp2(S - m); row-sum ----
    float lsum = 0.f;
#pragma unroll
    for (int jb = 0; jb < 4; ++jb)
#pragma unroll
      for (int r = 0; r < 4; ++r) {
        float e = __builtin_amdgcn_exp2f(s[jb][r] - m_run);
        s[jb][r] = e;
        lsum += e;
      }
    lsum += __shfl_xor(lsum, 16);
    lsum += __shfl_xor(lsum, 32);
    l_run += lsum;

    // ---- P -> per-wave LDS strip (bf16), XOR-swizzled ----
#pragma unroll
    for (int jb = 0; jb < 4; ++jb) {
      uint2 pkv;
      pkv.x = pk2(s[jb][0], s[jb][1]);
      pkv.y = pk2(s[jb][2], s[jb][3]);
      int c = 2 * jb + (g >> 1);
      *reinterpret_cast<uint2*>(&myp[p * 64 + ((c ^ sw) << 3) + ((g & 1) << 2)]) = pkv;
    }

    // ---- O += P V ----
    short8 pa0 = *reinterpret_cast<const short8*>(&myp[p * 64 + c0]);
    short8 pa1 = *reinterpret_cast<const short8*>(&myp[p * 64 + c1]);
    __builtin_amdgcn_s_setprio(1);
#pragma unroll
    for (int nb = 0; nb < 4; ++nb) {
      const u16* vb = &Vs[buf][(nb * 16 + p) * 64];
      short8 v0 = *reinterpret_cast<const short8*>(vb + c0);
      short8 v1 = *reinterpret_cast<const short8*>(vb + c1);
      oacc[nb] = __builtin_amdgcn_mfma_f32_16x16x32_bf16(pa0, v0, oacc[nb], 0, 0, 0);
      oacc[nb] = __builtin_amdgcn_mfma_f32_16x16x32_bf16(pa1, v1, oacc[nb], 0, 0, 0);
    }
    __builtin_amdgcn_s_setprio(0);

    __syncthreads();
    buf ^= 1;
  }

  // ---- finalize: divide by row sum, store bf16 to ao[b, q, h*64+d] ----
  float li[4];
#pragma unroll
  for (int r = 0; r < 4; ++r) li[r] = 1.f / __shfl(l_run, g * 4 + r);
  u16* obase = ao + ((size_t)(b * 1024 + qrow)) * 768 + h * 64;
#pragma unroll
  for (int nb = 0; nb < 4; ++nb)
#pragma unroll
    for (int r = 0; r < 4; ++r)
      obase[(size_t)(g * 4 + r) * 768 + nb * 16 + p] = f2bf(oacc[nb][r] * li[r]);
}

// ---------------- launch ----------------
extern "C" void kernel_launch(void* const* d_in, const int* in_sizes, int n_in,
                              void* d_out, int out_size, void* d_ws, size_t ws_size,
                              hipStream_t stream) {
  const float* x = (const float*)d_in[0];      // [8,1024,768]
  const float* Wqkv = (const float*)d_in[1];   // [768,2304]
  const float* bqkv = (const float*)d_in[2];   // [2304]
  const float* Wfc = (const float*)d_in[3];    // [768,768]
  const float* bfc = (const float*)d_in[4];    // [768]
  float* out = (float*)d_out;                  // [8,1024,768] f32

  char* ws = (char*)d_ws;
  u16* xb    = (u16*)(ws);                 // 12,582,912 B : x bf16 [8192][768]
  u16* wqkvT = (u16*)(ws + 12582912);      //  3,538,944 B : [2304][768]
  u16* wfcT  = (u16*)(ws + 16121856);      //  1,179,648 B : [768][768]
  u16* qh    = (u16*)(ws + 17301504);      // 12,582,912 B : [96][1024][64] (scaled)
  u16* kh    = (u16*)(ws + 29884416);      // 12,582,912 B : [96][1024][64]
  u16* vt    = (u16*)(ws + 55050240);      // 12,582,912 B : [96][64][1024]
  u16* ao    = (u16*)(ws + 67633152);      // 12,582,912 B : [8192][768]

  cvt_bf16_kernel<<<2048, 256, 0, stream>>>(x, xb, (8192 * 768) / 8);
  trcvt_kernel<<<12 * 36, 256, 0, stream>>>(Wqkv, wqkvT, 768, 2304);
  trcvt_kernel<<<12 * 12, 256, 0, stream>>>(Wfc, wfcT, 768, 768);
  gemm_bt<2><<<64 * 18, 256, 0, stream>>>(xb, wqkvT, bqkv, nullptr, qh, kh, vt, 2304);
  attn_kernel<<<96 * 8, 512, 0, stream>>>(qh, kh, vt, ao);
  gemm_bt<0><<<64 * 6, 256, 0, stream>>>(ao, wfcT, bfc, out, nullptr, nullptr, nullptr, 768);
}

// Round 12
// 133.285 us; speedup vs baseline: 1.2416x; 1.0706x over previous
//
#include <hip/hip_runtime.h>
#include <hip/hip_bf16.h>

// MultiHeadSelfAttention: B=8 N=1024 E=768 H=12 D=64
// Pipeline: cvt(x) / transpose-cvt(Wqkv,Wfc)
//           -> GEMM1 (R6 proven 2-phase dbuf 128^2; epilogue -> qh/kh/vh
//              [b,h,n,d] contiguous; Q pre-scaled by 1/sqrt(768)*log2e)
//           -> trv (vh -> vt [b,h,d,n], LDS-tiled -- coalesced both sides;
//              R11 showed GEMM-direct vt scatter costs +18us on GEMM1)
//           -> flash attention (exp2 softmax + defer-max + pk2, R11-proven)
//           -> GEMM2 (same GEMM template, f32 out + bias)
// GEMM: 128x128 tile, BK=32, 256 thr / 4 waves, dbuf 32KB LDS, one
// __syncthreads per K-iter; LDS swizzle chunk^((row>>1)&3) (0 conflicts, R5).
// ws usage: ~80 MB.

typedef unsigned short u16;
typedef unsigned int u32;
typedef __attribute__((ext_vector_type(8))) short short8;  // 8 x bf16 (4 VGPR)
typedef __attribute__((ext_vector_type(4))) float f32x4;

#define DEV static __device__ __forceinline__

DEV u16 f2bf(float f) {  // round-to-nearest-even f32 -> bf16 bits
  union { float f; u32 u; } v; v.f = f;
  return (u16)((v.u + 0x7FFFu + ((v.u >> 16) & 1u)) >> 16);
}

DEV u32 pk2(float lo, float hi) {  // pack 2 f32 -> 2 bf16 (RNE)
  union { __hip_bfloat162 h2; u32 u; } v;
  v.h2.x = __float2bfloat16(lo);
  v.h2.y = __float2bfloat16(hi);
  return v.u;
}

DEV void gload_lds16(const void* g, void* l) {
  // LDS dest is wave-uniform base; HW writes lane i at base + i*16B.
  __builtin_amdgcn_global_load_lds(
      (const __attribute__((address_space(1))) void*)g,
      (__attribute__((address_space(3))) void*)l, 16, 0, 0);
}

// ---------------- f32 -> bf16 elementwise (8 elems/thread) ----------------
__global__ void cvt_bf16_kernel(const float* __restrict__ in, u16* __restrict__ out, int n8) {
  int idx = blockIdx.x * blockDim.x + threadIdx.x;
  int stride = gridDim.x * blockDim.x;
  for (int i = idx; i < n8; i += stride) {
    float4 a = reinterpret_cast<const float4*>(in)[2 * i];
    float4 b = reinterpret_cast<const float4*>(in)[2 * i + 1];
    uint4 o;
    o.x = f2bf(a.x) | ((u32)f2bf(a.y) << 16);
    o.y = f2bf(a.z) | ((u32)f2bf(a.w) << 16);
    o.z = f2bf(b.x) | ((u32)f2bf(b.y) << 16);
    o.w = f2bf(b.z) | ((u32)f2bf(b.w) << 16);
    reinterpret_cast<uint4*>(out)[i] = o;
  }
}

// ------------- W [K][Nn] f32 -> Wt [Nn][K] bf16, 64x64 LDS tiles -------------
__global__ void trcvt_kernel(const float* __restrict__ in, u16* __restrict__ out,
                             int K, int Nn) {
  __shared__ u16 tile[64][72];
  int ntiles = Nn >> 6;
  int tk = blockIdx.x / ntiles, tn = blockIdx.x % ntiles;
  int k0 = tk << 6, n0 = tn << 6;
  int t = threadIdx.x;
  int r = t >> 4;            // 0..15
  int c4 = (t & 15) << 2;    // 0,4,..,60
#pragma unroll
  for (int ps = 0; ps < 4; ++ps) {
    int k = r + ps * 16;
    float4 v = *reinterpret_cast<const float4*>(&in[(size_t)(k0 + k) * Nn + n0 + c4]);
    tile[c4 + 0][k] = f2bf(v.x);
    tile[c4 + 1][k] = f2bf(v.y);
    tile[c4 + 2][k] = f2bf(v.z);
    tile[c4 + 3][k] = f2bf(v.w);
  }
  __syncthreads();
  int nr = t >> 3;           // 0..31
  int c8 = (t & 7) << 3;     // 0..56
#pragma unroll
  for (int ps = 0; ps < 2; ++ps) {
    int n = nr + ps * 32;
    uint4 v = *reinterpret_cast<const uint4*>(&tile[n][c8]);
    *reinterpret_cast<uint4*>(&out[(size_t)(n0 + n) * K + k0 + c8]) = v;
  }
}

// ------- vh [bh][n][64] -> vt [bh][64][n] (64-n tiles per (b,h)) -------
__global__ void trv_kernel(const u16* __restrict__ vh, u16* __restrict__ vt) {
  __shared__ u16 tile[64][72];
  int nt = blockIdx.x & 15;    // n tile 0..15
  int bh = blockIdx.x >> 4;    // 0..95
  int n0 = nt << 6;
  int t = threadIdx.x;
  int nr = t >> 3;             // 0..31
  int d8 = (t & 7) << 3;
  const u16* src = vh + ((size_t)bh * 1024 + n0) * 64;
#pragma unroll
  for (int ps = 0; ps < 2; ++ps) {
    int n = nr + ps * 32;
    uint4 v = *reinterpret_cast<const uint4*>(&src[(size_t)n * 64 + d8]);
    const u16* e = reinterpret_cast<const u16*>(&v);
#pragma unroll
    for (int j = 0; j < 8; ++j) tile[d8 + j][n] = e[j];
  }
  __syncthreads();
  u16* dst = vt + ((size_t)bh * 64) * 1024 + n0;
#pragma unroll
  for (int ps = 0; ps < 2; ++ps) {
    int d = nr + ps * 32;
    uint4 v = *reinterpret_cast<const uint4*>(&tile[d][d8]);
    *reinterpret_cast<uint4*>(&dst[(size_t)d * 1024 + d8]) = v;
  }
}

// ---------------- dbuf bf16 GEMM (R6 proven), K fixed = 768 ----------------
// MODE 0: f32 flat out.  MODE 2: split epilogue to qh/kh/vh [b,h,n,d]
// (contiguous d per 16-lane group -> coalesced); Q scaled by 1/sqrt(768)*log2e.
template <int MODE>
__global__ __launch_bounds__(256, 4) void gemm_bt(
    const u16* __restrict__ A, const u16* __restrict__ Bt,
    const float* __restrict__ bias, void* __restrict__ Cout,
    u16* __restrict__ qh, u16* __restrict__ kh, u16* __restrict__ vh,
    int Nn) {
  __shared__ u16 As[2][128 * 32];   // 16 KB
  __shared__ u16 Bs[2][128 * 32];   // 16 KB
  const int nTn = Nn >> 7;
  const int nwg = gridDim.x;
  int wg = blockIdx.x;
  wg = (wg & 7) * (nwg >> 3) + (wg >> 3);   // XCD swizzle (nwg % 8 == 0)
  const int tm = wg / nTn, tn = wg % nTn;
  const int m0 = tm << 7, n0 = tn << 7;
  const int tid = threadIdx.x;
  const int w = tid >> 6, lane = tid & 63;
  const int g = lane >> 4, p = lane & 15;
  const int wr = w >> 1, wc = w & 1;        // wave -> 64x64 out at (wr*64, wc*64)

  // staging: one gload = 16 rows x 32 elems; lane = srow*4 + sc.
  // LDS(row, c) holds global chunk c ^ ((row>>1)&3) -> pre-swizzled source.
  const int srow = lane >> 2;               // 0..15
  const int schunk = (lane & 3) ^ ((srow >> 1) & 3);
  const u16* Asrc = A + (size_t)(m0 + srow) * 768 + schunk * 8;
  const u16* Bsrc = Bt + (size_t)(n0 + srow) * 768 + schunk * 8;
  // frag read: global chunk g of row (16-aligned)+p is at LDS chunk g^((p>>1)&3)
  const int csw = (g ^ ((p >> 1) & 3)) << 3;  // u16 offset within row

  f32x4 acc[4][4] = {};

#define STAGE(kt, sbuf)                                                         \
  do {                                                                          \
    _Pragma("unroll")                                                           \
    for (int i = 0; i < 2; ++i) {                                               \
      int trow = w * 32 + i * 16;                                               \
      gload_lds16(Asrc + (size_t)trow * 768 + (kt) * 32, &As[sbuf][trow * 32]); \
      gload_lds16(Bsrc + (size_t)trow * 768 + (kt) * 32, &Bs[sbuf][trow * 32]); \
    }                                                                           \
  } while (0)

  // prologue: stage tile 0 (syncthreads drains vmcnt -> tile 0 ready)
  STAGE(0, 0);
  __syncthreads();

  int buf = 0;
  for (int k = 0; k < 24; ++k) {
    const u16* as = As[buf];
    const u16* bs = Bs[buf];
    short8 af[4], bf[4];
#pragma unroll
    for (int mb = 0; mb < 4; ++mb)
      af[mb] = *reinterpret_cast<const short8*>(&as[(wr * 64 + mb * 16 + p) * 32 + csw]);
#pragma unroll
    for (int nb = 0; nb < 4; ++nb)
      bf[nb] = *reinterpret_cast<const short8*>(&bs[(wc * 64 + nb * 16 + p) * 32 + csw]);
    if (k < 23) STAGE(k + 1, buf ^ 1);
#pragma unroll
    for (int mb = 0; mb < 4; ++mb)
#pragma unroll
      for (int nb = 0; nb < 4; ++nb)
        acc[mb][nb] = __builtin_amdgcn_mfma_f32_16x16x32_bf16(af[mb], bf[nb], acc[mb][nb], 0, 0, 0);
    __syncthreads();
    buf ^= 1;
  }
#undef STAGE

  // Q scale includes log2(e): softmax runs in exp2 domain downstream.
  const float qscale = 0.05205878290161879f;  // 1/sqrt(768) * log2(e)
#pragma unroll
  for (int nb = 0; nb < 4; ++nb) {
    int ncol = n0 + wc * 64 + nb * 16 + p;
    float bv = bias[ncol];
    if (MODE == 0) {
#pragma unroll
      for (int mb = 0; mb < 4; ++mb)
#pragma unroll
        for (int r = 0; r < 4; ++r) {
          int m = m0 + wr * 64 + mb * 16 + g * 4 + r;  // C/D: row=(lane>>4)*4+reg
          ((float*)Cout)[(size_t)m * Nn + ncol] = acc[mb][nb][r] + bv;
        }
    } else {
      int h64 = ncol >> 6;                 // 0..35
      int which = h64 / 12;                // 0=q 1=k 2=v
      int hh = h64 - which * 12;
      int d = ncol & 63;
      u16* dst = which == 0 ? qh : (which == 1 ? kh : vh);
      float sc = which == 0 ? qscale : 1.f;
#pragma unroll
      for (int mb = 0; mb < 4; ++mb)
#pragma unroll
        for (int r = 0; r < 4; ++r) {
          int m = m0 + wr * 64 + mb * 16 + g * 4 + r;
          int bb = m >> 10, nr = m & 1023;
          dst[(((size_t)bb * 12 + hh) * 1024 + nr) * 64 + d] = f2bf((acc[mb][nb][r] + bv) * sc);
        }
    }
  }
}

// ---------------- flash attention (exp2 softmax + defer-max, R11-proven) ----------------
// grid: bh(96) * 8 q-tiles of 128 rows; 512 thr / 8 waves, wave owns 16 q-rows.
// S in log2 domain (Q pre-scaled by 1/sqrt(768)*log2e): P = exp2(S - m).
// Defer-max (T13): skip O-rescale while tile-max growth <= 8 (P <= 2^8, f32 acc).
__global__ __launch_bounds__(512, 6) void attn_kernel(
    const u16* __restrict__ qh, const u16* __restrict__ kh,
    const u16* __restrict__ vt, u16* __restrict__ ao) {
  __shared__ u16 Ks[2][64 * 64];
  __shared__ u16 Vs[2][64 * 64];
  __shared__ u16 Ps[8][16 * 64];
  const int bid = blockIdx.x;
  const int qt = bid & 7;
  const int bh = bid >> 3;
  const int b = bh / 12, h = bh % 12;
  const int tid = threadIdx.x;
  const int w = tid >> 6, lane = tid & 63;
  const int g = lane >> 4, p = lane & 15;
  const int qrow = qt * 128 + w * 16;

  const u16* qbase = qh + ((size_t)bh * 1024 + qrow + p) * 64;
  short8 qf0 = *reinterpret_cast<const short8*>(qbase + g * 8);
  short8 qf1 = *reinterpret_cast<const short8*>(qbase + 32 + g * 8);

  const int ci = w * 64 + lane;              // 0..511
  const int crow = ci >> 3;                  // 0..63
  const int csw = (ci & 7) ^ (crow & 7);     // swizzled source chunk
  const u16* ksrc = kh + (((size_t)bh * 1024 + crow) << 6) + csw * 8;
  const u16* vsrc = vt + ((size_t)bh * 64 + crow) * 1024 + csw * 8;
  u16* myp = Ps[w];

  const int sw = p & 7;
  const int c0 = (g ^ sw) << 3;
  const int c1 = ((4 + g) ^ sw) << 3;

  float m_run = -1e30f, l_run = 0.f;
  f32x4 oacc[4] = {};

  gload_lds16(ksrc, &Ks[0][w * 512]);
  gload_lds16(vsrc, &Vs[0][w * 512]);
  __syncthreads();

  int buf = 0;
  for (int kt = 0; kt < 1024; kt += 64) {
    if (kt < 960) {
      gload_lds16(ksrc + ((kt + 64) << 6), &Ks[buf ^ 1][w * 512]);
      gload_lds16(vsrc + (kt + 64), &Vs[buf ^ 1][w * 512]);
    }

    // ---- St = K Q^T (log2 domain) ----
    f32x4 s[4];
    __builtin_amdgcn_s_setprio(1);
#pragma unroll
    for (int jb = 0; jb < 4; ++jb) {
      const u16* kb = &Ks[buf][(jb * 16 + p) * 64];
      short8 k0 = *reinterpret_cast<const short8*>(kb + c0);
      short8 k1 = *reinterpret_cast<const short8*>(kb + c1);
      f32x4 z = {};
      z = __builtin_amdgcn_mfma_f32_16x16x32_bf16(k0, qf0, z, 0, 0, 0);
      z = __builtin_amdgcn_mfma_f32_16x16x32_bf16(k1, qf1, z, 0, 0, 0);
      s[jb] = z;
    }
    __builtin_amdgcn_s_setprio(0);

    // ---- tile max (row q = p; replicated over g after shfl) ----
    float tmax = -1e30f;
#pragma unroll
    for (int jb = 0; jb < 4; ++jb)
#pragma unroll
      for (int r = 0; r < 4; ++r) tmax = fmaxf(tmax, s[jb][r]);
    tmax = fmaxf(tmax, __shfl_xor(tmax, 16));
    tmax = fmaxf(tmax, __shfl_xor(tmax, 32));

    // ---- defer-max: rescale only when growth > 8 (log2 units) ----
    if (!__all(tmax - m_run <= 8.f)) {
      float m_new = fmaxf(m_run, tmax);
      float alpha = __builtin_amdgcn_exp2f(m_run - m_new);
      float al[4];
#pragma unroll
      for (int r = 0; r < 4; ++r) al[r] = __shfl(alpha, g * 4 + r);
#pragma unroll
      for (int nb = 0; nb < 4; ++nb)
#pragma unroll
        for (int r = 0; r < 4; ++r) oacc[nb][r] *= al[r];
      l_run *= alpha;
      m_run = m_new;
    }

    // ---- P = exp2(S - m); row-sum ----
    float lsum = 0.f;
#pragma unroll
    for (int jb = 0; jb < 4; ++jb)
#pragma unroll
      for (int r = 0; r < 4; ++r) {
        float e = __builtin_amdgcn_exp2f(s[jb][r] - m_run);
        s[jb][r] = e;
        lsum += e;
      }
    lsum += __shfl_xor(lsum, 16);
    lsum += __shfl_xor(lsum, 32);
    l_run += lsum;

    // ---- P -> per-wave LDS strip (bf16), XOR-swizzled ----
#pragma unroll
    for (int jb = 0; jb < 4; ++jb) {
      uint2 pkv;
      pkv.x = pk2(s[jb][0], s[jb][1]);
      pkv.y = pk2(s[jb][2], s[jb][3]);
      int c = 2 * jb + (g >> 1);
      *reinterpret_cast<uint2*>(&myp[p * 64 + ((c ^ sw) << 3) + ((g & 1) << 2)]) = pkv;
    }

    // ---- O += P V ----
    short8 pa0 = *reinterpret_cast<const short8*>(&myp[p * 64 + c0]);
    short8 pa1 = *reinterpret_cast<const short8*>(&myp[p * 64 + c1]);
    __builtin_amdgcn_s_setprio(1);
#pragma unroll
    for (int nb = 0; nb < 4; ++nb) {
      const u16* vb = &Vs[buf][(nb * 16 + p) * 64];
      short8 v0 = *reinterpret_cast<const short8*>(vb + c0);
      short8 v1 = *reinterpret_cast<const short8*>(vb + c1);
      oacc[nb] = __builtin_amdgcn_mfma_f32_16x16x32_bf16(pa0, v0, oacc[nb], 0, 0, 0);
      oacc[nb] = __builtin_amdgcn_mfma_f32_16x16x32_bf16(pa1, v1, oacc[nb], 0, 0, 0);
    }
    __builtin_amdgcn_s_setprio(0);

    __syncthreads();
    buf ^= 1;
  }

  // ---- finalize: divide by row sum, store bf16 to ao[b, q, h*64+d] ----
  float li[4];
#pragma unroll
  for (int r = 0; r < 4; ++r) li[r] = 1.f / __shfl(l_run, g * 4 + r);
  u16* obase = ao + ((size_t)(b * 1024 + qrow)) * 768 + h * 64;
#pragma unroll
  for (int nb = 0; nb < 4; ++nb)
#pragma unroll
    for (int r = 0; r < 4; ++r)
      obase[(size_t)(g * 4 + r) * 768 + nb * 16 + p] = f2bf(oacc[nb][r] * li[r]);
}

// ---------------- launch ----------------
extern "C" void kernel_launch(void* const* d_in, const int* in_sizes, int n_in,
                              void* d_out, int out_size, void* d_ws, size_t ws_size,
                              hipStream_t stream) {
  const float* x = (const float*)d_in[0];      // [8,1024,768]
  const float* Wqkv = (const float*)d_in[1];   // [768,2304]
  const float* bqkv = (const float*)d_in[2];   // [2304]
  const float* Wfc = (const float*)d_in[3];    // [768,768]
  const float* bfc = (const float*)d_in[4];    // [768]
  float* out = (float*)d_out;                  // [8,1024,768] f32

  char* ws = (char*)d_ws;
  u16* xb    = (u16*)(ws);                 // 12,582,912 B : x bf16 [8192][768]
  u16* wqkvT = (u16*)(ws + 12582912);      //  3,538,944 B : [2304][768]
  u16* wfcT  = (u16*)(ws + 16121856);      //  1,179,648 B : [768][768]
  u16* qh    = (u16*)(ws + 17301504);      // 12,582,912 B : [96][1024][64] (scaled)
  u16* kh    = (u16*)(ws + 29884416);      // 12,582,912 B : [96][1024][64]
  u16* vh    = (u16*)(ws + 42467328);      // 12,582,912 B : [96][1024][64]
  u16* vt    = (u16*)(ws + 55050240);      // 12,582,912 B : [96][64][1024]
  u16* ao    = (u16*)(ws + 67633152);      // 12,582,912 B : [8192][768]

  cvt_bf16_kernel<<<2048, 256, 0, stream>>>(x, xb, (8192 * 768) / 8);
  trcvt_kernel<<<12 * 36, 256, 0, stream>>>(Wqkv, wqkvT, 768, 2304);
  trcvt_kernel<<<12 * 12, 256, 0, stream>>>(Wfc, wfcT, 768, 768);
  gemm_bt<2><<<64 * 18, 256, 0, stream>>>(xb, wqkvT, bqkv, nullptr, qh, kh, vh, 2304);
  trv_kernel<<<96 * 16, 256, 0, stream>>>(vh, vt);
  attn_kernel<<<96 * 8, 512, 0, stream>>>(qh, kh, vt, ao);
  gemm_bt<0><<<64 * 6, 256, 0, stream>>>(ao, wfcT, bfc, out, nullptr, nullptr, nullptr, 768);
}

// Round 13
// 123.965 us; speedup vs baseline: 1.3350x; 1.0752x over previous
//
#include <hip/hip_runtime.h>
#include <hip/hip_bf16.h>

// MultiHeadSelfAttention: B=8 N=1024 E=768 H=12 D=64
// Pipeline (4 launches):
//   prep  : cvt(x->bf16) + transpose-cvt(Wqkv) + transpose-cvt(Wfc), fused
//   GEMM1 : R6-proven 2-phase dbuf 128^2; epilogue -> qh/kh [b,h,n,d]
//           (Q pre-scaled by 1/sqrt(768)*log2e); V-tiles transposed through
//           LDS (stride-136 pad, 2-way-free banks) DIRECT to vt [b,h,d,n]
//           with 16B/lane coalesced stores (fixes R11's scatter mistake).
//   attn  : flash attention (exp2 softmax + defer-max + pk2, R11-proven)
//   GEMM2 : same GEMM template, f32 out + bias
// GEMM: 128x128 tile, BK=32, 256 thr / 4 waves, dbuf 32KB LDS, one
// __syncthreads per K-iter; LDS swizzle chunk^((row>>1)&3) (0 conflicts, R5).
// ws usage: ~80 MB.

typedef unsigned short u16;
typedef unsigned int u32;
typedef __attribute__((ext_vector_type(8))) short short8;  // 8 x bf16 (4 VGPR)
typedef __attribute__((ext_vector_type(4))) float f32x4;

#define DEV static __device__ __forceinline__

DEV u16 f2bf(float f) {  // round-to-nearest-even f32 -> bf16 bits
  union { float f; u32 u; } v; v.f = f;
  return (u16)((v.u + 0x7FFFu + ((v.u >> 16) & 1u)) >> 16);
}

DEV u32 pk2(float lo, float hi) {  // pack 2 f32 -> 2 bf16 (RNE)
  union { __hip_bfloat162 h2; u32 u; } v;
  v.h2.x = __float2bfloat16(lo);
  v.h2.y = __float2bfloat16(hi);
  return v.u;
}

DEV void gload_lds16(const void* g, void* l) {
  // LDS dest is wave-uniform base; HW writes lane i at base + i*16B.
  __builtin_amdgcn_global_load_lds(
      (const __attribute__((address_space(1))) void*)g,
      (__attribute__((address_space(3))) void*)l, 16, 0, 0);
}

// ---------------- prep: cvt(x) + trcvt(Wqkv) + trcvt(Wfc), one launch ----------------
// blocks [0,432): Wqkv [768][2304] -> [2304][768] bf16 (64x64 LDS tiles)
// blocks [432,576): Wfc [768][768] -> [768][768] bf16
// blocks [576,2624): x f32 -> bf16, 8 elems/thread grid-stride
__global__ void prep_kernel(const float* __restrict__ x, u16* __restrict__ xb,
                            const float* __restrict__ Wq, u16* __restrict__ WqT,
                            const float* __restrict__ Wf, u16* __restrict__ WfT) {
  __shared__ u16 tile[64][72];
  const int b = blockIdx.x;
  const int t = threadIdx.x;
  if (b < 576) {
    const float* in;
    u16* out;
    int Nn, bid;
    if (b < 432) { in = Wq; out = WqT; Nn = 2304; bid = b; }
    else         { in = Wf; out = WfT; Nn = 768;  bid = b - 432; }
    const int K = 768;
    int ntiles = Nn >> 6;
    int tk = bid / ntiles, tn = bid % ntiles;
    int k0 = tk << 6, n0 = tn << 6;
    int r = t >> 4;            // 0..15
    int c4 = (t & 15) << 2;    // 0,4,..,60
#pragma unroll
    for (int ps = 0; ps < 4; ++ps) {
      int k = r + ps * 16;
      float4 v = *reinterpret_cast<const float4*>(&in[(size_t)(k0 + k) * Nn + n0 + c4]);
      tile[c4 + 0][k] = f2bf(v.x);
      tile[c4 + 1][k] = f2bf(v.y);
      tile[c4 + 2][k] = f2bf(v.z);
      tile[c4 + 3][k] = f2bf(v.w);
    }
    __syncthreads();
    int nr = t >> 3;           // 0..31
    int c8 = (t & 7) << 3;     // 0..56
#pragma unroll
    for (int ps = 0; ps < 2; ++ps) {
      int n = nr + ps * 32;
      uint4 v = *reinterpret_cast<const uint4*>(&tile[n][c8]);
      *reinterpret_cast<uint4*>(&out[(size_t)(n0 + n) * K + k0 + c8]) = v;
    }
  } else {
    const int n8 = (8192 * 768) / 8;
    int idx = (b - 576) * 256 + t;
    const int stride = 2048 * 256;
    for (int i = idx; i < n8; i += stride) {
      float4 a = reinterpret_cast<const float4*>(x)[2 * i];
      float4 c = reinterpret_cast<const float4*>(x)[2 * i + 1];
      uint4 o;
      o.x = f2bf(a.x) | ((u32)f2bf(a.y) << 16);
      o.y = f2bf(a.z) | ((u32)f2bf(a.w) << 16);
      o.z = f2bf(c.x) | ((u32)f2bf(c.y) << 16);
      o.w = f2bf(c.z) | ((u32)f2bf(c.w) << 16);
      reinterpret_cast<uint4*>(xb)[i] = o;
    }
  }
}

// ---------------- dbuf bf16 GEMM (R6 proven), K fixed = 768 ----------------
// MODE 0: f32 flat out.
// MODE 2: Q/K-blocks -> qh/kh [b,h,n,d] (Q scaled by 1/sqrt(768)*log2e);
//         V-blocks (n0>=1536, uniform) -> LDS-transposed, stored to
//         vt [b,h,d,n] with coalesced 16B/lane rows.
template <int MODE>
__global__ __launch_bounds__(256, 4) void gemm_bt(
    const u16* __restrict__ A, const u16* __restrict__ Bt,
    const float* __restrict__ bias, void* __restrict__ Cout,
    u16* __restrict__ qh, u16* __restrict__ kh, u16* __restrict__ vt,
    int Nn) {
  // 34816 u16 = 69.6KB? NO: 17408 u16 = 34816 B. Layout:
  //   [0,4096)   As buf0      [4096,8192)  As buf1
  //   [8192,12288) Bs buf0    [12288,16384) Bs buf1
  //   transpose phase reuses [0, 17408) as 128 rows x stride 136
  __shared__ u16 SMEM[17408];
  u16* const As0 = SMEM;
  u16* const As1 = SMEM + 4096;
  u16* const Bs0 = SMEM + 8192;
  u16* const Bs1 = SMEM + 12288;
  const int nTn = Nn >> 7;
  const int nwg = gridDim.x;
  int wg = blockIdx.x;
  wg = (wg & 7) * (nwg >> 3) + (wg >> 3);   // XCD swizzle (nwg % 8 == 0)
  const int tm = wg / nTn, tn = wg % nTn;
  const int m0 = tm << 7, n0 = tn << 7;
  const int tid = threadIdx.x;
  const int w = tid >> 6, lane = tid & 63;
  const int g = lane >> 4, p = lane & 15;
  const int wr = w >> 1, wc = w & 1;        // wave -> 64x64 out at (wr*64, wc*64)

  // staging: one gload = 16 rows x 32 elems; lane = srow*4 + sc.
  // LDS(row, c) holds global chunk c ^ ((row>>1)&3) -> pre-swizzled source.
  const int srow = lane >> 2;               // 0..15
  const int schunk = (lane & 3) ^ ((srow >> 1) & 3);
  const u16* Asrc = A + (size_t)(m0 + srow) * 768 + schunk * 8;
  const u16* Bsrc = Bt + (size_t)(n0 + srow) * 768 + schunk * 8;
  // frag read: global chunk g of row (16-aligned)+p is at LDS chunk g^((p>>1)&3)
  const int csw = (g ^ ((p >> 1) & 3)) << 3;  // u16 offset within row

  f32x4 acc[4][4] = {};

#define STAGE(kt, ap, bp)                                                       \
  do {                                                                          \
    _Pragma("unroll")                                                           \
    for (int i = 0; i < 2; ++i) {                                               \
      int trow = w * 32 + i * 16;                                               \
      gload_lds16(Asrc + (size_t)trow * 768 + (kt) * 32, (ap) + trow * 32);     \
      gload_lds16(Bsrc + (size_t)trow * 768 + (kt) * 32, (bp) + trow * 32);     \
    }                                                                           \
  } while (0)

  // prologue: stage tile 0 (syncthreads drains vmcnt -> tile 0 ready)
  STAGE(0, As0, Bs0);
  __syncthreads();

  int buf = 0;
  for (int k = 0; k < 24; ++k) {
    const u16* as = buf ? As1 : As0;
    const u16* bs = buf ? Bs1 : Bs0;
    short8 af[4], bf[4];
#pragma unroll
    for (int mb = 0; mb < 4; ++mb)
      af[mb] = *reinterpret_cast<const short8*>(&as[(wr * 64 + mb * 16 + p) * 32 + csw]);
#pragma unroll
    for (int nb = 0; nb < 4; ++nb)
      bf[nb] = *reinterpret_cast<const short8*>(&bs[(wc * 64 + nb * 16 + p) * 32 + csw]);
    if (k < 23) STAGE(k + 1, buf ? As0 : As1, buf ? Bs0 : Bs1);
#pragma unroll
    for (int mb = 0; mb < 4; ++mb)
#pragma unroll
      for (int nb = 0; nb < 4; ++nb)
        acc[mb][nb] = __builtin_amdgcn_mfma_f32_16x16x32_bf16(af[mb], bf[nb], acc[mb][nb], 0, 0, 0);
    __syncthreads();
    buf ^= 1;
  }
#undef STAGE

  // Q scale includes log2(e): softmax runs in exp2 domain downstream.
  const float qscale = 0.05205878290161879f;  // 1/sqrt(768) * log2(e)
  if (MODE == 0) {
#pragma unroll
    for (int nb = 0; nb < 4; ++nb) {
      int ncol = n0 + wc * 64 + nb * 16 + p;
      float bv = bias[ncol];
#pragma unroll
      for (int mb = 0; mb < 4; ++mb)
#pragma unroll
        for (int r = 0; r < 4; ++r) {
          int m = m0 + wr * 64 + mb * 16 + g * 4 + r;  // C/D: row=(lane>>4)*4+reg
          ((float*)Cout)[(size_t)m * Nn + ncol] = acc[mb][nb][r] + bv;
        }
    }
  } else if (n0 < 1536) {
    // ---- Q/K blocks: [b,h,n,d] contiguous stores (R6-proven) ----
#pragma unroll
    for (int nb = 0; nb < 4; ++nb) {
      int ncol = n0 + wc * 64 + nb * 16 + p;
      float bv = bias[ncol];
      int h64 = ncol >> 6;                 // 0..23
      int which = h64 / 12;                // 0=q 1=k
      int hh = h64 - which * 12;
      int d = ncol & 63;
      u16* dst = which == 0 ? qh : kh;
      float sc = which == 0 ? qscale : 1.f;
#pragma unroll
      for (int mb = 0; mb < 4; ++mb)
#pragma unroll
        for (int r = 0; r < 4; ++r) {
          int m = m0 + wr * 64 + mb * 16 + g * 4 + r;
          int bb = m >> 10, nr = m & 1023;
          dst[(((size_t)bb * 12 + hh) * 1024 + nr) * 64 + d] = f2bf((acc[mb][nb][r] + bv) * sc);
        }
    }
  } else {
    // ---- V blocks: transpose 128x128 tile through LDS -> vt[bh][d][n] ----
    // write: SMEM[nl*136 + ml] (stride 136 u16: write banks 2-way, read 2-way)
#pragma unroll
    for (int nb = 0; nb < 4; ++nb) {
      int nl = wc * 64 + nb * 16 + p;
      float bv = bias[n0 + nl];
#pragma unroll
      for (int mb = 0; mb < 4; ++mb) {
        int mlb = wr * 64 + mb * 16 + g * 4;
        uint2 pkv;
        pkv.x = (u32)f2bf(acc[mb][nb][0] + bv) | ((u32)f2bf(acc[mb][nb][1] + bv) << 16);
        pkv.y = (u32)f2bf(acc[mb][nb][2] + bv) | ((u32)f2bf(acc[mb][nb][3] + bv) << 16);
        *reinterpret_cast<uint2*>(&SMEM[nl * 136 + mlb]) = pkv;
      }
    }
    __syncthreads();
    // read rows of the transposed tile, store coalesced (8 lanes = 256B/row)
    const int hhb = (n0 - 1536) >> 6;
    const int bb = m0 >> 10;
    const int nseq0 = m0 & 1023;
    const int c16 = (tid & 7) * 16;
#pragma unroll
    for (int ps = 0; ps < 4; ++ps) {
      int nl = (tid >> 3) + ps * 32;
      int hh = hhb + (nl >> 6);
      int d = nl & 63;
      u16* dst = vt + (((size_t)(bb * 12 + hh) * 64 + d) << 10) + nseq0 + c16;
      uint4 v0 = *reinterpret_cast<const uint4*>(&SMEM[nl * 136 + c16]);
      uint4 v1 = *reinterpret_cast<const uint4*>(&SMEM[nl * 136 + c16 + 8]);
      *reinterpret_cast<uint4*>(dst) = v0;
      *reinterpret_cast<uint4*>(dst + 8) = v1;
    }
  }
}

// ---------------- flash attention (exp2 softmax + defer-max, R11-proven) ----------------
// grid: bh(96) * 8 q-tiles of 128 rows; 512 thr / 8 waves, wave owns 16 q-rows.
// S in log2 domain (Q pre-scaled by 1/sqrt(768)*log2e): P = exp2(S - m).
// Defer-max (T13): skip O-rescale while tile-max growth <= 8 (P <= 2^8, f32 acc).
__global__ __launch_bounds__(512, 6) void attn_kernel(
    const u16* __restrict__ qh, const u16* __restrict__ kh,
    const u16* __restrict__ vt, u16* __restrict__ ao) {
  __shared__ u16 Ks[2][64 * 64];
  __shared__ u16 Vs[2][64 * 64];
  __shared__ u16 Ps[8][16 * 64];
  const int bid = blockIdx.x;
  const int qt = bid & 7;
  const int bh = bid >> 3;
  const int b = bh / 12, h = bh % 12;
  const int tid = threadIdx.x;
  const int w = tid >> 6, lane = tid & 63;
  const int g = lane >> 4, p = lane & 15;
  const int qrow = qt * 128 + w * 16;

  const u16* qbase = qh + ((size_t)bh * 1024 + qrow + p) * 64;
  short8 qf0 = *reinterpret_cast<const short8*>(qbase + g * 8);
  short8 qf1 = *reinterpret_cast<const short8*>(qbase + 32 + g * 8);

  const int ci = w * 64 + lane;              // 0..511
  const int crow = ci >> 3;                  // 0..63
  const int csw = (ci & 7) ^ (crow & 7);     // swizzled source chunk
  const u16* ksrc = kh + (((size_t)bh * 1024 + crow) << 6) + csw * 8;
  const u16* vsrc = vt + ((size_t)bh * 64 + crow) * 1024 + csw * 8;
  u16* myp = Ps[w];

  const int sw = p & 7;
  const int c0 = (g ^ sw) << 3;
  const int c1 = ((4 + g) ^ sw) << 3;

  float m_run = -1e30f, l_run = 0.f;
  f32x4 oacc[4] = {};

  gload_lds16(ksrc, &Ks[0][w * 512]);
  gload_lds16(vsrc, &Vs[0][w * 512]);
  __syncthreads();

  int buf = 0;
  for (int kt = 0; kt < 1024; kt += 64) {
    if (kt < 960) {
      gload_lds16(ksrc + ((kt + 64) << 6), &Ks[buf ^ 1][w * 512]);
      gload_lds16(vsrc + (kt + 64), &Vs[buf ^ 1][w * 512]);
    }

    // ---- St = K Q^T (log2 domain) ----
    f32x4 s[4];
    __builtin_amdgcn_s_setprio(1);
#pragma unroll
    for (int jb = 0; jb < 4; ++jb) {
      const u16* kb = &Ks[buf][(jb * 16 + p) * 64];
      short8 k0 = *reinterpret_cast<const short8*>(kb + c0);
      short8 k1 = *reinterpret_cast<const short8*>(kb + c1);
      f32x4 z = {};
      z = __builtin_amdgcn_mfma_f32_16x16x32_bf16(k0, qf0, z, 0, 0, 0);
      z = __builtin_amdgcn_mfma_f32_16x16x32_bf16(k1, qf1, z, 0, 0, 0);
      s[jb] = z;
    }
    __builtin_amdgcn_s_setprio(0);

    // ---- tile max (row q = p; replicated over g after shfl) ----
    float tmax = -1e30f;
#pragma unroll
    for (int jb = 0; jb < 4; ++jb)
#pragma unroll
      for (int r = 0; r < 4; ++r) tmax = fmaxf(tmax, s[jb][r]);
    tmax = fmaxf(tmax, __shfl_xor(tmax, 16));
    tmax = fmaxf(tmax, __shfl_xor(tmax, 32));

    // ---- defer-max: rescale only when growth > 8 (log2 units) ----
    if (!__all(tmax - m_run <= 8.f)) {
      float m_new = fmaxf(m_run, tmax);
      float alpha = __builtin_amdgcn_exp2f(m_run - m_new);
      float al[4];
#pragma unroll
      for (int r = 0; r < 4; ++r) al[r] = __shfl(alpha, g * 4 + r);
#pragma unroll
      for (int nb = 0; nb < 4; ++nb)
#pragma unroll
        for (int r = 0; r < 4; ++r) oacc[nb][r] *= al[r];
      l_run *= alpha;
      m_run = m_new;
    }

    // ---- P = exp2(S - m); row-sum ----
    float lsum = 0.f;
#pragma unroll
    for (int jb = 0; jb < 4; ++jb)
#pragma unroll
      for (int r = 0; r < 4; ++r) {
        float e = __builtin_amdgcn_exp2f(s[jb][r] - m_run);
        s[jb][r] = e;
        lsum += e;
      }
    lsum += __shfl_xor(lsum, 16);
    lsum += __shfl_xor(lsum, 32);
    l_run += lsum;

    // ---- P -> per-wave LDS strip (bf16), XOR-swizzled ----
#pragma unroll
    for (int jb = 0; jb < 4; ++jb) {
      uint2 pkv;
      pkv.x = pk2(s[jb][0], s[jb][1]);
      pkv.y = pk2(s[jb][2], s[jb][3]);
      int c = 2 * jb + (g >> 1);
      *reinterpret_cast<uint2*>(&myp[p * 64 + ((c ^ sw) << 3) + ((g & 1) << 2)]) = pkv;
    }

    // ---- O += P V ----
    short8 pa0 = *reinterpret_cast<const short8*>(&myp[p * 64 + c0]);
    short8 pa1 = *reinterpret_cast<const short8*>(&myp[p * 64 + c1]);
    __builtin_amdgcn_s_setprio(1);
#pragma unroll
    for (int nb = 0; nb < 4; ++nb) {
      const u16* vb = &Vs[buf][(nb * 16 + p) * 64];
      short8 v0 = *reinterpret_cast<const short8*>(vb + c0);
      short8 v1 = *reinterpret_cast<const short8*>(vb + c1);
      oacc[nb] = __builtin_amdgcn_mfma_f32_16x16x32_bf16(pa0, v0, oacc[nb], 0, 0, 0);
      oacc[nb] = __builtin_amdgcn_mfma_f32_16x16x32_bf16(pa1, v1, oacc[nb], 0, 0, 0);
    }
    __builtin_amdgcn_s_setprio(0);

    __syncthreads();
    buf ^= 1;
  }

  // ---- finalize: divide by row sum, store bf16 to ao[b, q, h*64+d] ----
  float li[4];
#pragma unroll
  for (int r = 0; r < 4; ++r) li[r] = 1.f / __shfl(l_run, g * 4 + r);
  u16* obase = ao + ((size_t)(b * 1024 + qrow)) * 768 + h * 64;
#pragma unroll
  for (int nb = 0; nb < 4; ++nb)
#pragma unroll
    for (int r = 0; r < 4; ++r)
      obase[(size_t)(g * 4 + r) * 768 + nb * 16 + p] = f2bf(oacc[nb][r] * li[r]);
}

// ---------------- launch ----------------
extern "C" void kernel_launch(void* const* d_in, const int* in_sizes, int n_in,
                              void* d_out, int out_size, void* d_ws, size_t ws_size,
                              hipStream_t stream) {
  const float* x = (const float*)d_in[0];      // [8,1024,768]
  const float* Wqkv = (const float*)d_in[1];   // [768,2304]
  const float* bqkv = (const float*)d_in[2];   // [2304]
  const float* Wfc = (const float*)d_in[3];    // [768,768]
  const float* bfc = (const float*)d_in[4];    // [768]
  float* out = (float*)d_out;                  // [8,1024,768] f32

  char* ws = (char*)d_ws;
  u16* xb    = (u16*)(ws);                 // 12,582,912 B : x bf16 [8192][768]
  u16* wqkvT = (u16*)(ws + 12582912);      //  3,538,944 B : [2304][768]
  u16* wfcT  = (u16*)(ws + 16121856);      //  1,179,648 B : [768][768]
  u16* qh    = (u16*)(ws + 17301504);      // 12,582,912 B : [96][1024][64] (scaled)
  u16* kh    = (u16*)(ws + 29884416);      // 12,582,912 B : [96][1024][64]
  u16* vt    = (u16*)(ws + 55050240);      // 12,582,912 B : [96][64][1024]
  u16* ao    = (u16*)(ws + 67633152);      // 12,582,912 B : [8192][768]

  prep_kernel<<<2624, 256, 0, stream>>>(x, xb, Wqkv, wqkvT, Wfc, wfcT);
  gemm_bt<2><<<64 * 18, 256, 0, stream>>>(xb, wqkvT, bqkv, nullptr, qh, kh, vt, 2304);
  attn_kernel<<<96 * 8, 512, 0, stream>>>(qh, kh, vt, ao);
  gemm_bt<0><<<64 * 6, 256, 0, stream>>>(ao, wfcT, bfc, out, nullptr, nullptr, nullptr, 768);
}